// Round 1
// baseline (906.675 us; speedup 1.0000x reference)
//
#include <hip/hip_runtime.h>
#include <hip/hip_fp16.h>

#define BB 64
#define SS 32
#define DD 512
#define NMEM 4096
#define KTOP 4
#define EPSV 1e-8f

typedef _Float16 f16;
typedef f16 f16x8 __attribute__((ext_vector_type(8)));
typedef f16 f16x4 __attribute__((ext_vector_type(4)));
typedef float f32x4 __attribute__((ext_vector_type(4)));

// ---------------- K_w: convert expert weights f32 -> f16 ----------------
__global__ void k_wconv(const float* __restrict__ s0, const float* __restrict__ s1,
                        const float* __restrict__ s2, const float* __restrict__ s3,
                        f16* __restrict__ d0, f16* __restrict__ d1,
                        f16* __restrict__ d2, f16* __restrict__ d3) {
    const float* s; f16* d;
    switch (blockIdx.y) {
        case 0: s = s0; d = d0; break;
        case 1: s = s1; d = d1; break;
        case 2: s = s2; d = d2; break;
        default: s = s3; d = d3; break;
    }
    size_t i = ((size_t)blockIdx.x * 256 + threadIdx.x) * 4;   // 4*512*512 elems per array
    float4 v = *(const float4*)(s + i);
    f16x4 o;
    o[0] = (f16)v.x; o[1] = (f16)v.y; o[2] = (f16)v.z; o[3] = (f16)v.w;
    *(f16x4*)(d + i) = o;
}

// ---------------- K0: query means + normalized query means ----------------
// mod 0 (gen image): query = text; mod 1 (gen text): query = image
__global__ void k_qmean(const float* __restrict__ image, const float* __restrict__ text,
                        float* __restrict__ qmean, float* __restrict__ qn) {
    int mod = blockIdx.x >> 6;
    int b = blockIdx.x & 63;
    const float* q = (mod == 0) ? text : image;
    int t = threadIdx.x;  // 256
    const float* base = q + (size_t)b * SS * DD + t * 2;
    float ax = 0.f, ay = 0.f;
#pragma unroll
    for (int s = 0; s < SS; ++s) {
        float2 v = *(const float2*)(base + (size_t)s * DD);
        ax += v.x; ay += v.y;
    }
    ax *= (1.f / SS); ay *= (1.f / SS);
    float* qm = qmean + ((size_t)mod * BB + b) * DD;
    qm[t * 2] = ax; qm[t * 2 + 1] = ay;
    __shared__ float red[256];
    red[t] = ax * ax + ay * ay;
    __syncthreads();
    for (int off = 128; off > 0; off >>= 1) {
        if (t < off) red[t] += red[t + off];
        __syncthreads();
    }
    __shared__ float s_inv;
    if (t == 0) s_inv = 1.f / fmaxf(sqrtf(red[0]), EPSV);
    __syncthreads();
    float inv = s_inv;
    float* qo = qn + ((size_t)mod * BB + b) * DD;
    qo[t * 2] = ax * inv; qo[t * 2 + 1] = ay * inv;
}

// ---------------- K1: memory-row means + fused cosine sim ----------------
// mod 0: mem_image, mod 1: mem_text.  One block per (mod, n).
// v2: float4 (16B/lane) loads; threads t and t+128 split the 32 rows by parity.
__global__ void k_memmean_sim(const float* __restrict__ mem_image, const float* __restrict__ mem_text,
                              const float* __restrict__ qn, float* __restrict__ mmean,
                              float* __restrict__ sim) {
    int mod = blockIdx.x >> 12;   // grid 8192
    int n = blockIdx.x & 4095;
    const float* mem = (mod == 0) ? mem_image : mem_text;
    int t = threadIdx.x;          // 256
    int cg = t & 127;             // column group: columns cg*4 .. cg*4+3
    int half = t >> 7;            // row parity: rows s = 2*i + half
    const float* base = mem + (size_t)n * SS * DD + (size_t)half * DD + cg * 4;
    float ax = 0.f, ay = 0.f, az = 0.f, aw = 0.f;
#pragma unroll
    for (int i = 0; i < SS / 2; ++i) {
        float4 v = *(const float4*)(base + (size_t)(i * 2) * DD);
        ax += v.x; ay += v.y; az += v.z; aw += v.w;
    }
    __shared__ float part[128][4];
    if (half) { part[cg][0] = ax; part[cg][1] = ay; part[cg][2] = az; part[cg][3] = aw; }
    __syncthreads();
    __shared__ float red[128], red2[128];
    __shared__ float smn[512];
    if (!half) {
        const float inv = 1.f / SS;
        ax = (ax + part[cg][0]) * inv;
        ay = (ay + part[cg][1]) * inv;
        az = (az + part[cg][2]) * inv;
        aw = (aw + part[cg][3]) * inv;
        float4 o; o.x = ax; o.y = ay; o.z = az; o.w = aw;
        *(float4*)(mmean + ((size_t)mod * NMEM + n) * DD + cg * 4) = o;
        red[cg] = ax * ax + ay * ay + az * az + aw * aw;
        red2[cg] = ax + ay + az + aw;
    }
    __syncthreads();
    for (int off = 64; off > 0; off >>= 1) {
        if (t < off) { red[t] += red[t + off]; red2[t] += red2[t + off]; }
        __syncthreads();
    }
    __shared__ float s_scale;
    if (t == 0) {
        float norm = sqrtf(red[0]);
        float valid = (red2[0] != 0.f) ? 1.f : 0.f;
        s_scale = valid / fmaxf(norm, EPSV);
    }
    __syncthreads();
    if (!half) {
        float sc = s_scale;
        smn[cg * 4] = ax * sc; smn[cg * 4 + 1] = ay * sc;
        smn[cg * 4 + 2] = az * sc; smn[cg * 4 + 3] = aw * sc;
    }
    __syncthreads();

    int w = t >> 6, lane = t & 63;
    float4 m0 = *(const float4*)(&smn[lane * 8]);
    float4 m1v = *(const float4*)(&smn[lane * 8 + 4]);
    for (int b = w; b < BB; b += 4) {
        const float* qp = qn + ((size_t)mod * BB + b) * DD + lane * 8;
        float4 q0 = *(const float4*)qp;
        float4 q1 = *(const float4*)(qp + 4);
        float d = m0.x * q0.x + m0.y * q0.y + m0.z * q0.z + m0.w * q0.w
                + m1v.x * q1.x + m1v.y * q1.y + m1v.z * q1.z + m1v.w * q1.w;
#pragma unroll
        for (int o = 32; o > 0; o >>= 1) d += __shfl_down(d, o);
        if (lane == 0) sim[((size_t)mod * BB + b) * NMEM + n] = d;
    }
}

// ---------------- K2: stable top-4 per (mod, b) ----------------
__global__ void k_topk(const float* __restrict__ sim, int* __restrict__ topk) {
    int mod = blockIdx.x >> 6;
    int b = blockIdx.x & 63;
    int lane = threadIdx.x;  // 64
    const float* sp = sim + ((size_t)mod * BB + b) * NMEM;
    float tv[4] = {-1e30f, -1e30f, -1e30f, -1e30f};
    int ti[4] = {2147483647, 2147483647, 2147483647, 2147483647};
    for (int i = 0; i < NMEM / 64; ++i) {
        int n = i * 64 + lane;
        float v = sp[n];
        if (v > tv[3]) {
            int p = 3;
            while (p > 0 && v > tv[p - 1]) { tv[p] = tv[p - 1]; ti[p] = ti[p - 1]; --p; }
            tv[p] = v; ti[p] = n;
        }
    }
    __shared__ float cv[256];
    __shared__ int ci[256];
#pragma unroll
    for (int j = 0; j < 4; ++j) { cv[lane * 4 + j] = tv[j]; ci[lane * 4 + j] = ti[j]; }
    __syncthreads();
    if (lane == 0) {
        int* out = topk + (mod * BB + b) * KTOP;
        for (int k = 0; k < KTOP; ++k) {
            float bv = -1e30f; int bi = 2147483647; int bj = -1;
            for (int j = 0; j < 256; ++j) {
                if (cv[j] > bv || (cv[j] == bv && ci[j] < bi)) { bv = cv[j]; bi = ci[j]; bj = j; }
            }
            out[k] = bi;
            cv[bj] = -1e30f; ci[bj] = 2147483647;
        }
    }
}

// ---------------- K3: softmax routing scores (f32) ----------------
__global__ void k_score(const float* __restrict__ qmean, const float* __restrict__ mmean,
                        const int* __restrict__ topk,
                        const float* __restrict__ irw, const float* __restrict__ irb,
                        const float* __restrict__ itw, const float* __restrict__ itb,
                        const float* __restrict__ trw, const float* __restrict__ trb,
                        const float* __restrict__ ttw, const float* __restrict__ ttb,
                        float* __restrict__ score) {
    int mod = blockIdx.x >> 6;
    int b = blockIdx.x & 63;
    const float* rem_w = mod ? trw : irw;
    const float* rem_b = mod ? trb : irb;
    const float* ret_w = mod ? ttw : itw;
    const float* ret_b = mod ? ttb : itb;
    __shared__ float x0[512];
    __shared__ float x1[4][512];
    __shared__ float accs[4][4];
    int t = threadIdx.x, w = t >> 6, lane = t & 63;
    const int* idx = topk + (mod * BB + b) * KTOP;
    int i0 = idx[0], i1 = idx[1], i2 = idx[2], i3 = idx[3];
    const float* q = qmean + ((size_t)mod * BB + b) * DD;
    const float* p0 = mmean + ((size_t)mod * NMEM + i0) * DD;
    const float* p1 = mmean + ((size_t)mod * NMEM + i1) * DD;
    const float* p2 = mmean + ((size_t)mod * NMEM + i2) * DD;
    const float* p3 = mmean + ((size_t)mod * NMEM + i3) * DD;
    for (int d0 = t; d0 < DD; d0 += 256) {
        x0[d0] = q[d0];
        x1[0][d0] = p0[d0]; x1[1][d0] = p1[d0]; x1[2][d0] = p2[d0]; x1[3][d0] = p3[d0];
    }
    __syncthreads();
    float sk[4] = {0.f, 0.f, 0.f, 0.f};
    float4 qa = *(const float4*)(&x0[lane * 8]);
    float4 qb = *(const float4*)(&x0[lane * 8 + 4]);
    for (int e = w; e < DD; e += 4) {
        const float* wr = rem_w + (size_t)e * DD + lane * 8;
        const float* tr = ret_w + (size_t)e * DD + lane * 8;
        float4 wa = *(const float4*)wr, wb = *(const float4*)(wr + 4);
        float4 ta = *(const float4*)tr, tb = *(const float4*)(tr + 4);
        float pr = wa.x * qa.x + wa.y * qa.y + wa.z * qa.z + wa.w * qa.w
                 + wb.x * qb.x + wb.y * qb.y + wb.z * qb.z + wb.w * qb.w;
#pragma unroll
        for (int o = 1; o < 64; o <<= 1) pr += __shfl_xor(pr, o);
        float re = pr + rem_b[e];
#pragma unroll
        for (int k = 0; k < 4; ++k) {
            float4 xa = *(const float4*)(&x1[k][lane * 8]);
            float4 xb = *(const float4*)(&x1[k][lane * 8 + 4]);
            float pt = ta.x * xa.x + ta.y * xa.y + ta.z * xa.z + ta.w * xa.w
                     + tb.x * xb.x + tb.y * xb.y + tb.z * xb.z + tb.w * xb.w;
#pragma unroll
            for (int o = 1; o < 64; o <<= 1) pt += __shfl_xor(pt, o);
            sk[k] += re * (pt + ret_b[e]);
        }
    }
    if (lane == 0) { accs[w][0] = sk[0]; accs[w][1] = sk[1]; accs[w][2] = sk[2]; accs[w][3] = sk[3]; }
    __syncthreads();
    if (t == 0) {
        float s[4];
        for (int k = 0; k < 4; ++k) s[k] = accs[0][k] + accs[1][k] + accs[2][k] + accs[3][k];
        float mx = fmaxf(fmaxf(s[0], s[1]), fmaxf(s[2], s[3]));
        float ex[4], sum = 0.f;
        for (int k = 0; k < 4; ++k) { ex[k] = expf(s[k] - mx); sum += ex[k]; }
        for (int k = 0; k < 4; ++k) score[(mod * BB + b) * KTOP + k] = ex[k] / sum;
    }
}

// ---------------- K4: layer1 GEMM  H = relu(X @ W1^T + b1), f16 MFMA ----------------
// grid (8 Ntile, 32 Mtile, mod*4+k), block 256
__launch_bounds__(256)
__global__ void k_layer1(const float* __restrict__ mem_image, const float* __restrict__ mem_text,
                         const int* __restrict__ topk, const f16* __restrict__ ew1h,
                         const float* __restrict__ eb1_img, const float* __restrict__ eb1_txt,
                         f16* __restrict__ H) {
    int bx = blockIdx.x, by = blockIdx.y, mk = blockIdx.z;
    int mod = mk >> 2, k = mk & 3;
    const float* mem = (mod == 0) ? mem_image : mem_text;
    const float* eb1 = (mod == 0) ? eb1_img : eb1_txt;

    __shared__ f16 As[64][40];
    __shared__ f16 Bs[64][40];

    int t = threadIdx.x;
    int lrow = t >> 2;
    int lcol = (t & 3) * 8;
    int rg = by * 64 + lrow;
    int bb = rg >> 5, ss = rg & 31;
    int mrow = topk[(mod * BB + bb) * KTOP + k];
    const float* aptr = mem + ((size_t)mrow * SS + ss) * DD + lcol;
    const f16* bptr = ew1h + ((size_t)mk * DD + bx * 64 + lrow) * DD + lcol;

    int w = t >> 6, lane = t & 63;
    int wm = (w >> 1) * 32, wn = (w & 1) * 32;
    int quad = lane >> 4, l16 = lane & 15;

    f32x4 acc[2][2] = {};
    for (int kk = 0; kk < DD; kk += 32) {
        float4 a0 = *(const float4*)(aptr + kk);
        float4 a1 = *(const float4*)(aptr + kk + 4);
        f16x8 bv = *(const f16x8*)(bptr + kk);
        f16x8 af;
        af[0] = (f16)a0.x; af[1] = (f16)a0.y; af[2] = (f16)a0.z; af[3] = (f16)a0.w;
        af[4] = (f16)a1.x; af[5] = (f16)a1.y; af[6] = (f16)a1.z; af[7] = (f16)a1.w;
        *(f16x8*)(&As[lrow][lcol]) = af;
        *(f16x8*)(&Bs[lrow][lcol]) = bv;
        __syncthreads();
#pragma unroll
        for (int tm = 0; tm < 2; ++tm) {
            f16x8 a = *(const f16x8*)(&As[wm + tm * 16 + l16][quad * 8]);
#pragma unroll
            for (int tn = 0; tn < 2; ++tn) {
                f16x8 bf = *(const f16x8*)(&Bs[wn + tn * 16 + l16][quad * 8]);
                acc[tm][tn] = __builtin_amdgcn_mfma_f32_16x16x32_f16(a, bf, acc[tm][tn], 0, 0, 0);
            }
        }
        __syncthreads();
    }
#pragma unroll
    for (int tm = 0; tm < 2; ++tm)
#pragma unroll
        for (int tn = 0; tn < 2; ++tn) {
            int colg = bx * 64 + wn + tn * 16 + l16;
            float bias = eb1[k * DD + colg];
#pragma unroll
            for (int r = 0; r < 4; ++r) {
                int rowg = by * 64 + wm + tm * 16 + quad * 4 + r;
                float v = fmaxf(acc[tm][tn][r] + bias, 0.f);
                H[((size_t)mk * 2048 + rowg) * DD + colg] = (f16)v;
            }
        }
}

// ---------------- K5: layer2 GEMM + score-weighted sum + masked outputs ----------------
// grid (8 Ntile, 32 Mtile, mod), block 256
__launch_bounds__(256)
__global__ void k_layer2(const f16* __restrict__ H, const f16* __restrict__ ew2h,
                         const float* __restrict__ eb2_img, const float* __restrict__ eb2_txt,
                         const float* __restrict__ score,
                         const float* __restrict__ image, const float* __restrict__ text,
                         const int* __restrict__ m1, const int* __restrict__ m2,
                         float* __restrict__ out) {
    int bx = blockIdx.x, by = blockIdx.y, mod = blockIdx.z;
    __shared__ f16 As[64][40];
    __shared__ f16 Bs[64][40];
    __shared__ float s_sc[2][4];
    int t = threadIdx.x;
    if (t < 8) {
        int bl = t >> 2, kq = t & 3;
        s_sc[bl][kq] = score[(mod * BB + by * 2 + bl) * KTOP + kq];
    }
    int lrow = t >> 2, lcol = (t & 3) * 8;
    int w = t >> 6, lane = t & 63;
    int wm = (w >> 1) * 32, wn = (w & 1) * 32;
    int quad = lane >> 4, l16 = lane & 15;

    float fin[2][2][4] = {};
    for (int k = 0; k < 4; ++k) {
        f32x4 acc[2][2] = {};
        const f16* aptr = H + ((size_t)(mod * 4 + k) * 2048 + by * 64 + lrow) * DD + lcol;
        const f16* bptr = ew2h + ((size_t)(mod * 4 + k) * DD + bx * 64 + lrow) * DD + lcol;
        for (int kk = 0; kk < DD; kk += 32) {
            *(f16x8*)(&As[lrow][lcol]) = *(const f16x8*)(aptr + kk);
            *(f16x8*)(&Bs[lrow][lcol]) = *(const f16x8*)(bptr + kk);
            __syncthreads();
#pragma unroll
            for (int tm = 0; tm < 2; ++tm) {
                f16x8 a = *(const f16x8*)(&As[wm + tm * 16 + l16][quad * 8]);
#pragma unroll
                for (int tn = 0; tn < 2; ++tn) {
                    f16x8 bf = *(const f16x8*)(&Bs[wn + tn * 16 + l16][quad * 8]);
                    acc[tm][tn] = __builtin_amdgcn_mfma_f32_16x16x32_f16(a, bf, acc[tm][tn], 0, 0, 0);
                }
            }
            __syncthreads();
        }
#pragma unroll
        for (int tm = 0; tm < 2; ++tm)
#pragma unroll
            for (int tn = 0; tn < 2; ++tn)
#pragma unroll
                for (int r = 0; r < 4; ++r) {
                    int rloc = wm + tm * 16 + quad * 4 + r;
                    fin[tm][tn][r] += s_sc[rloc >> 5][k] * acc[tm][tn][r];
                }
    }

    const float* eb2 = (mod == 0) ? eb2_img : eb2_txt;
    const float* orig = (mod == 0) ? image : text;
    float* out_comp = out + (size_t)mod * 1048576;
    float* out_gen = out + (size_t)(2 + mod) * 1048576;
#pragma unroll
    for (int tm = 0; tm < 2; ++tm)
#pragma unroll
        for (int tn = 0; tn < 2; ++tn) {
            int colg = bx * 64 + wn + tn * 16 + l16;
#pragma unroll
            for (int r = 0; r < 4; ++r) {
                int rowg = by * 64 + wm + tm * 16 + quad * 4 + r;
                int bl = (rowg >> 5) & 1;
                float g = fin[tm][tn][r];
                for (int k = 0; k < 4; ++k) g += s_sc[bl][k] * eb2[k * DD + colg];
                int bb = rowg >> 5;
                bool e1 = (m1[bb] == 1), e2 = (m2[bb] == 1);
                size_t off = (size_t)rowg * DD + colg;
                if (mod == 0) {
                    out_comp[off] = (!e1 && e2) ? g : orig[off];
                    out_gen[off] = e2 ? g : 0.f;
                } else {
                    out_comp[off] = (!e2 && e1) ? g : orig[off];
                    out_gen[off] = e1 ? g : 0.f;
                }
            }
        }
}

extern "C" void kernel_launch(void* const* d_in, const int* in_sizes, int n_in,
                              void* d_out, int out_size, void* d_ws, size_t ws_size,
                              hipStream_t stream) {
    const float* image = (const float*)d_in[0];
    const float* text = (const float*)d_in[1];
    const int* m1 = (const int*)d_in[2];
    const int* m2 = (const int*)d_in[3];
    const float* mem_image = (const float*)d_in[4];
    const float* mem_text = (const float*)d_in[5];
    const float* i_rem_w = (const float*)d_in[6];
    const float* i_rem_b = (const float*)d_in[7];
    const float* i_ret_w = (const float*)d_in[8];
    const float* i_ret_b = (const float*)d_in[9];
    const float* i_ew1 = (const float*)d_in[10];
    const float* i_eb1 = (const float*)d_in[11];
    const float* i_ew2 = (const float*)d_in[12];
    const float* i_eb2 = (const float*)d_in[13];
    const float* t_rem_w = (const float*)d_in[14];
    const float* t_rem_b = (const float*)d_in[15];
    const float* t_ret_w = (const float*)d_in[16];
    const float* t_ret_b = (const float*)d_in[17];
    const float* t_ew1 = (const float*)d_in[18];
    const float* t_eb1 = (const float*)d_in[19];
    const float* t_ew2 = (const float*)d_in[20];
    const float* t_eb2 = (const float*)d_in[21];

    char* ws = (char*)d_ws;
    float* qmean = (float*)(ws + 0);                 // [2][64][512] f32   256KB
    float* qn = (float*)(ws + 262144);               // [2][64][512] f32   256KB
    float* mmean = (float*)(ws + 524288);            // [2][4096][512] f32 16MB
    float* sim = (float*)(ws + 17301504);            // [2][64][4096] f32  2MB
    int* topk = (int*)(ws + 19398656);               // [2][64][4] int
    float* score = (float*)(ws + 19400704);          // [2][64][4] f32
    f16* ew1h = (f16*)(ws + 19402752);               // [2][4][512][512] f16 4MB
    f16* ew2h = (f16*)(ws + 23597056);               // [2][4][512][512] f16 4MB
    f16* H = (f16*)(ws + 27791360);                  // [2][4][2048][512] f16 16MB

    k_wconv<<<dim3(1024, 4), 256, 0, stream>>>(i_ew1, t_ew1, i_ew2, t_ew2,
                                               ew1h, ew1h + 1048576, ew2h, ew2h + 1048576);
    k_qmean<<<128, 256, 0, stream>>>(image, text, qmean, qn);
    k_memmean_sim<<<8192, 256, 0, stream>>>(mem_image, mem_text, qn, mmean, sim);
    k_topk<<<128, 64, 0, stream>>>(sim, topk);
    k_score<<<128, 256, 0, stream>>>(qmean, mmean, topk,
                                     i_rem_w, i_rem_b, i_ret_w, i_ret_b,
                                     t_rem_w, t_rem_b, t_ret_w, t_ret_b, score);
    k_layer1<<<dim3(8, 32, 8), 256, 0, stream>>>(mem_image, mem_text, topk, ew1h,
                                                 i_eb1, t_eb1, H);
    k_layer2<<<dim3(8, 32, 2), 256, 0, stream>>>(H, ew2h, i_eb2, t_eb2, score,
                                                 image, text, m1, m2, (float*)d_out);
}